// Round 5
// baseline (253.115 us; speedup 1.0000x reference)
//
#include <hip/hip_runtime.h>

typedef __attribute__((ext_vector_type(8))) short bf16x8;
typedef __attribute__((ext_vector_type(4))) float f32x4;
typedef __attribute__((ext_vector_type(16))) float f32x16;
typedef __attribute__((ext_vector_type(4))) int i32x4;

#define N_NODES 8192
#define D_IN    256
#define D_OUT   128
#define LOG2E   1.44269504088896f

__device__ __forceinline__ unsigned short bf16_rne(float f) {
  unsigned int u = __float_as_uint(f);
  u += 0x7fffu + ((u >> 16) & 1u);
  return (unsigned short)(u >> 16);
}
__device__ __forceinline__ float bf16_to_f(unsigned short s) {
  return __uint_as_float(((unsigned int)s) << 16);
}

// ---------------- k0a: split x (fp32) -> x_hi, x_lo (bf16) ----------------
__global__ __launch_bounds__(256) void k_split_x(const float* __restrict__ x,
                                                 unsigned short* __restrict__ xhi,
                                                 unsigned short* __restrict__ xlo) {
  int idx = (blockIdx.x * 256 + threadIdx.x) * 8;
  float4 v0 = *(const float4*)(x + idx);
  float4 v1 = *(const float4*)(x + idx + 4);
  float v[8] = {v0.x, v0.y, v0.z, v0.w, v1.x, v1.y, v1.z, v1.w};
  unsigned int hw[4], lw[4];
#pragma unroll
  for (int p = 0; p < 4; ++p) {
    unsigned short h0 = bf16_rne(v[2 * p]);
    unsigned short h1 = bf16_rne(v[2 * p + 1]);
    unsigned short l0 = bf16_rne(v[2 * p] - bf16_to_f(h0));
    unsigned short l1 = bf16_rne(v[2 * p + 1] - bf16_to_f(h1));
    hw[p] = (unsigned int)h0 | ((unsigned int)h1 << 16);
    lw[p] = (unsigned int)l0 | ((unsigned int)l1 << 16);
  }
  *(uint4*)(xhi + idx) = make_uint4(hw[0], hw[1], hw[2], hw[3]);
  *(uint4*)(xlo + idx) = make_uint4(lw[0], lw[1], lw[2], lw[3]);
}

// ------------- k0b: split + transpose W -> W_hiT, W_loT [128][256] -------------
__global__ __launch_bounds__(256) void k_split_w(const float* __restrict__ W,
                                                 unsigned short* __restrict__ whiT,
                                                 unsigned short* __restrict__ wloT) {
  int c = blockIdx.x;
  int k = threadIdx.x;
  float v = W[k * D_OUT + c];
  unsigned short h = bf16_rne(v);
  unsigned short l = bf16_rne(v - bf16_to_f(h));
  whiT[c * D_IN + k] = h;
  wloT[c * D_IN + k] = l;
}

// ---- k1: h = x @ W (split-bf16 MFMA) + fused src/dst dots + B-panel pack ----
__global__ __launch_bounds__(256) void k_h_gemm(const unsigned short* __restrict__ xhi,
                                                const unsigned short* __restrict__ xlo,
                                                const unsigned short* __restrict__ whiT,
                                                const unsigned short* __restrict__ wloT,
                                                const float* __restrict__ a_src,
                                                const float* __restrict__ a_dst,
                                                float* __restrict__ srcv,
                                                float* __restrict__ dstv,
                                                unsigned short* __restrict__ phi,
                                                unsigned short* __restrict__ plo) {
  __shared__ float h_s[32][128];
  const int t = threadIdx.x, l = t & 63, wv = t >> 6;
  const int i0 = blockIdx.x * 32;
  const int m = wv >> 1, nh = wv & 1;
  const int frow = l & 15, kq = l >> 4;
  const size_t arow = (size_t)(i0 + m * 16 + frow);
  const unsigned short* pah = xhi + arow * D_IN + kq * 8;
  const unsigned short* pal = xlo + arow * D_IN + kq * 8;
  f32x4 acc[4];
#pragma unroll
  for (int nf = 0; nf < 4; ++nf) acc[nf] = (f32x4){0.f, 0.f, 0.f, 0.f};
#pragma unroll
  for (int kk = 0; kk < 8; ++kk) {
    const int k0 = kk * 32;
    bf16x8 ah = *(const bf16x8*)(pah + k0);
    bf16x8 al = *(const bf16x8*)(pal + k0);
#pragma unroll
    for (int nf = 0; nf < 4; ++nf) {
      const int col = nh * 64 + nf * 16 + frow;
      bf16x8 bh = *(const bf16x8*)(whiT + (size_t)col * D_IN + k0 + kq * 8);
      bf16x8 bl = *(const bf16x8*)(wloT + (size_t)col * D_IN + k0 + kq * 8);
      acc[nf] = __builtin_amdgcn_mfma_f32_16x16x32_bf16(ah, bh, acc[nf], 0, 0, 0);
      acc[nf] = __builtin_amdgcn_mfma_f32_16x16x32_bf16(al, bh, acc[nf], 0, 0, 0);
      acc[nf] = __builtin_amdgcn_mfma_f32_16x16x32_bf16(ah, bl, acc[nf], 0, 0, 0);
    }
  }
#pragma unroll
  for (int nf = 0; nf < 4; ++nf)
#pragma unroll
    for (int r = 0; r < 4; ++r)
      h_s[m * 16 + kq * 4 + r][nh * 64 + nf * 16 + frow] = acc[nf][r];
  __syncthreads();

  if (t < 32) {
    float s = 0.f, d = 0.f;
#pragma unroll
    for (int c = 0; c < D_OUT; ++c) {
      float v = h_s[t][c];
      s += v * a_src[c];
      d += v * a_dst[c];
    }
    srcv[i0 + t] = s * LOG2E;
    dstv[i0 + t] = d * LOG2E;
  }

  {
    const int b = t >> 7, ct = (t >> 5) & 3, lw = t & 31;
    const size_t kg = (size_t)(i0 / 16 + b);
#pragma unroll
    for (int half = 0; half < 2; ++half) {
      const int lane = lw + 32 * half;
      unsigned int hw[4], lwd[4];
#pragma unroll
      for (int p = 0; p < 4; ++p) {
        float v0 = h_s[b * 16 + half * 8 + 2 * p][ct * 32 + lw];
        float v1 = h_s[b * 16 + half * 8 + 2 * p + 1][ct * 32 + lw];
        unsigned short h0 = bf16_rne(v0), h1 = bf16_rne(v1);
        unsigned short l0 = bf16_rne(v0 - bf16_to_f(h0));
        unsigned short l1 = bf16_rne(v1 - bf16_to_f(h1));
        hw[p] = (unsigned int)h0 | ((unsigned int)h1 << 16);
        lwd[p] = (unsigned int)l0 | ((unsigned int)l1 << 16);
      }
      const size_t off = ((kg * 4 + ct) * 64 + lane) * 8;
      *(uint4*)(phi + off) = make_uint4(hw[0], hw[1], hw[2], hw[3]);
      *(uint4*)(plo + off) = make_uint4(lwd[0], lwd[1], lwd[2], lwd[3]);
    }
  }
}

// ---------------- k3: fused masked-softmax aggregation (pipelined v5) ----------------
// grid 512 = 256 row-tiles x 2 j-halves; 512 threads = 8 waves: ch = wv>>2, js = wv&3.
// Per wave-iter: 32 consecutive j (full 128B adj lines). Software pipeline:
//   issue order per iter: B(it+1) [8 loads], sched_barrier, adj(it+2) [4 NT loads],
//   sched_barrier, then w(it)+MFMA(it). In-order vmcnt => waiting for B(it)
//   (issued last iter, BEFORE adj(it+1)... wait chain) leaves adj stages in flight:
//   adj gets 2 iterations of slack, B gets 1. No __syncthreads in the loop.
__global__ __launch_bounds__(512, 2) void k_gat(const int* __restrict__ adj,
                                                const float* __restrict__ srcv,
                                                const float* __restrict__ dstv,
                                                const unsigned short* __restrict__ phi,
                                                const unsigned short* __restrict__ plo,
                                                float* __restrict__ pnum,
                                                float* __restrict__ prsum) {
  __shared__ float dstv_s[4096];   // 16 KB: this block's j-half of dstv
  __shared__ float red[2][2048];   // 16 KB: js-reduction buffer
  __shared__ float rsl[4][32];

  const int t = threadIdx.x, l = t & 63, wv = t >> 6;
  const int ch = wv >> 2, js = wv & 3;
  const int bid = blockIdx.x;
  const int tile = bid & 255, jh = bid >> 8;
  const int i0 = tile * 32;
  const int r32 = l & 31, kh = l >> 5;

  {
    const float4* s4 = (const float4*)(dstv + jh * 4096);
    float4* d4 = (float4*)dstv_s;
    d4[t] = s4[t];
    d4[t + 512] = s4[t + 512];
  }
  const float s2 = srcv[i0 + r32];
  __syncthreads();   // drains everything; all pipelined loads issued after this

  // adj: lane (r32, kh) + js own 32-j slice; kh=0 covers ints [0,8)+[16,24), kh=1 [8,16)+[24,32)
  const int* adjp = adj + (size_t)(i0 + r32) * N_NODES + jh * 4096 + js * 32 + kh * 8;
  // panel bases (ushort units); fragment (kst, ct) at ((kst*4+ct)*64+l)*8
  const int kst0 = jh * 256 + js * 2;
  const unsigned short* pb0 = phi + ((size_t)(kst0 * 4 + ch * 2) * 64 + l) * 8;
  const unsigned short* pb1 = plo + ((size_t)(kst0 * 4 + ch * 2) * 64 + l) * 8;
  // per-it stride: 16384 ushorts; ks (+1 kst): 2048; ct: 512

  f32x16 acc0, acc1;
#pragma unroll
  for (int q = 0; q < 16; ++q) { acc0[q] = 0.f; acc1[q] = 0.f; }
  float rs = 0.f;

  i32x4 adjq[4][4];
  bf16x8 bq[2][8];

  // ---- prologue: B(0), then adj(0), adj(1) ----
#pragma unroll
  for (int ks = 0; ks < 2; ++ks)
#pragma unroll
    for (int ct = 0; ct < 2; ++ct) {
      bq[0][ks * 4 + ct * 2 + 0] = *(const bf16x8*)(pb0 + ks * 2048 + ct * 512);
      bq[0][ks * 4 + ct * 2 + 1] = *(const bf16x8*)(pb1 + ks * 2048 + ct * 512);
    }
#pragma unroll
  for (int s = 0; s < 2; ++s) {
    adjq[s][0] = __builtin_nontemporal_load((const i32x4*)(adjp + s * 128));
    adjq[s][1] = __builtin_nontemporal_load((const i32x4*)(adjp + s * 128 + 4));
    adjq[s][2] = __builtin_nontemporal_load((const i32x4*)(adjp + s * 128 + 16));
    adjq[s][3] = __builtin_nontemporal_load((const i32x4*)(adjp + s * 128 + 20));
  }
  __builtin_amdgcn_sched_barrier(0);

#pragma unroll
  for (int it = 0; it < 32; ++it) {
    const int sB = it & 1, sBn = (it + 1) & 1;
    const int sA = it & 3, sAi = (it + 2) & 3;
    const int itB = (it + 1 < 32) ? it + 1 : 31;
    const int itA = (it + 2 < 32) ? it + 2 : 31;

    // 1) issue B(it+1)  (L2-resident panels, coalesced)
#pragma unroll
    for (int ks = 0; ks < 2; ++ks)
#pragma unroll
      for (int ct = 0; ct < 2; ++ct) {
        bq[sBn][ks * 4 + ct * 2 + 0] = *(const bf16x8*)(pb0 + itB * 16384 + ks * 2048 + ct * 512);
        bq[sBn][ks * 4 + ct * 2 + 1] = *(const bf16x8*)(pb1 + itB * 16384 + ks * 2048 + ct * 512);
      }
    __builtin_amdgcn_sched_barrier(0);
    // 2) issue adj(it+2)  (HBM stream, nontemporal)
    adjq[sAi][0] = __builtin_nontemporal_load((const i32x4*)(adjp + itA * 128));
    adjq[sAi][1] = __builtin_nontemporal_load((const i32x4*)(adjp + itA * 128 + 4));
    adjq[sAi][2] = __builtin_nontemporal_load((const i32x4*)(adjp + itA * 128 + 16));
    adjq[sAi][3] = __builtin_nontemporal_load((const i32x4*)(adjp + itA * 128 + 20));
    __builtin_amdgcn_sched_barrier(0);

    // 3) w-compute(it) + MFMA(it)
    const int jl = it * 128 + js * 32 + kh * 8;
#pragma unroll
    for (int ks = 0; ks < 2; ++ks) {
      f32x4 dva = *(const f32x4*)&dstv_s[jl + ks * 16];
      f32x4 dvb = *(const f32x4*)&dstv_s[jl + ks * 16 + 4];
      i32x4 aa = adjq[sA][ks * 2];
      i32x4 ab = adjq[sA][ks * 2 + 1];
      float w[8];
#pragma unroll
      for (int e = 0; e < 4; ++e) {
        float e0 = s2 + dva[e]; e0 = fmaxf(e0, 0.2f * e0);
        float e1 = s2 + dvb[e]; e1 = fmaxf(e1, 0.2f * e1);
        w[e]     = (aa[e] > 0) ? exp2f(e0) : 0.f;
        w[4 + e] = (ab[e] > 0) ? exp2f(e1) : 0.f;
      }
      if (ch == 0)
        rs += ((w[0] + w[1]) + (w[2] + w[3])) + ((w[4] + w[5]) + (w[6] + w[7]));
      union { bf16x8 v; unsigned int u[4]; } af;
#pragma unroll
      for (int p = 0; p < 4; ++p)
        af.u[p] = (unsigned int)bf16_rne(w[2 * p]) | ((unsigned int)bf16_rne(w[2 * p + 1]) << 16);

      acc0 = __builtin_amdgcn_mfma_f32_32x32x16_bf16(af.v, bq[sB][ks * 4 + 0], acc0, 0, 0, 0);
      acc0 = __builtin_amdgcn_mfma_f32_32x32x16_bf16(af.v, bq[sB][ks * 4 + 1], acc0, 0, 0, 0);
      acc1 = __builtin_amdgcn_mfma_f32_32x32x16_bf16(af.v, bq[sB][ks * 4 + 2], acc1, 0, 0, 0);
      acc1 = __builtin_amdgcn_mfma_f32_32x32x16_bf16(af.v, bq[sB][ks * 4 + 3], acc1, 0, 0, 0);
    }
  }

  // rowsum across kh halves; stash per js
  rs += __shfl_xor(rs, 32);
  if (ch == 0 && kh == 0) rsl[js][r32] = rs;

  // js-reduction of numerators, 3 rounds through a 16 KB buffer
#pragma unroll
  for (int q = 1; q < 4; ++q) {
    if (js == q) {
#pragma unroll
      for (int reg = 0; reg < 16; ++reg) {
        red[ch][reg * 64 + l] = acc0[reg];
        red[ch][1024 + reg * 64 + l] = acc1[reg];
      }
    }
    __syncthreads();
    if (js == 0) {
#pragma unroll
      for (int reg = 0; reg < 16; ++reg) {
        acc0[reg] += red[ch][reg * 64 + l];
        acc1[reg] += red[ch][1024 + reg * 64 + l];
      }
    }
    __syncthreads();
  }

  if (js == 0) {
    float* pn = pnum + (size_t)bid * 4096;
#pragma unroll
    for (int reg = 0; reg < 16; ++reg) {
      const int row = (reg & 3) + 8 * (reg >> 2) + 4 * kh;
      pn[row * 128 + ch * 64 + r32] = acc0[reg];
      pn[row * 128 + ch * 64 + 32 + r32] = acc1[reg];
    }
    if (ch == 0 && kh == 0)
      prsum[bid * 32 + r32] = (rsl[0][r32] + rsl[1][r32]) + (rsl[2][r32] + rsl[3][r32]);
  }
}

// ---------------- k4: merge j-halves, divide by rowsum ----------------
__global__ __launch_bounds__(1024) void k_comb(const float* __restrict__ pnum,
                                               const float* __restrict__ prsum,
                                               float* __restrict__ out) {
  const int tile = blockIdx.x, t = threadIdx.x;
  const float4 a = ((const float4*)(pnum + (size_t)tile * 4096))[t];
  const float4 b = ((const float4*)(pnum + (size_t)(256 + tile) * 4096))[t];
  const int row = t >> 5;
  const float r = prsum[tile * 32 + row] + prsum[(256 + tile) * 32 + row];
  float4 o;
  o.x = (a.x + b.x) / r;
  o.y = (a.y + b.y) / r;
  o.z = (a.z + b.z) / r;
  o.w = (a.w + b.w) / r;
  ((float4*)(out + (size_t)tile * 4096))[t] = o;
}

extern "C" void kernel_launch(void* const* d_in, const int* in_sizes, int n_in,
                              void* d_out, int out_size, void* d_ws, size_t ws_size,
                              hipStream_t stream) {
  const float* x     = (const float*)d_in[0];
  const int*   adj   = (const int*)d_in[1];
  const float* W     = (const float*)d_in[2];
  const float* a_src = (const float*)d_in[3];
  const float* a_dst = (const float*)d_in[4];
  float* out = (float*)d_out;

  char* ws = (char*)d_ws;
  unsigned short* xhi  = (unsigned short*)(ws);                               // 4 MB (dead after k_h_gemm)
  unsigned short* xlo  = (unsigned short*)(ws + (4 << 20));                   // 4 MB (dead after k_h_gemm)
  unsigned short* whiT = (unsigned short*)(ws + (8 << 20));                   // 64 KB
  unsigned short* wloT = (unsigned short*)(ws + (8 << 20) + (64 << 10));      // 64 KB
  unsigned short* phi  = (unsigned short*)(ws + (8 << 20) + (128 << 10));     // 2 MB
  unsigned short* plo  = (unsigned short*)(ws + (10 << 20) + (128 << 10));    // 2 MB
  float*          srcv = (float*)(ws + (12 << 20) + (128 << 10));             // 32 KB
  float*          dstv = (float*)(ws + (12 << 20) + (160 << 10));             // 32 KB
  float*          pnum = (float*)(ws);                                        // 8 MB, aliases xhi/xlo
  float*          prsum= (float*)(ws + (12 << 20) + (192 << 10));             // 64 KB

  k_split_x<<<dim3(1024), dim3(256), 0, stream>>>(x, xhi, xlo);
  k_split_w<<<dim3(128), dim3(256), 0, stream>>>(W, whiT, wloT);
  k_h_gemm<<<dim3(256), dim3(256), 0, stream>>>(xhi, xlo, whiT, wloT,
                                                a_src, a_dst, srcv, dstv, phi, plo);
  k_gat<<<dim3(512), dim3(512), 0, stream>>>(adj, srcv, dstv, phi, plo, pnum, prsum);
  k_comb<<<dim3(256), dim3(1024), 0, stream>>>(pnum, prsum, out);
}

// Round 6
// 188.511 us; speedup vs baseline: 1.3427x; 1.3427x over previous
//
#include <hip/hip_runtime.h>

typedef __attribute__((ext_vector_type(8))) short bf16x8;
typedef __attribute__((ext_vector_type(4))) float f32x4;
typedef __attribute__((ext_vector_type(16))) float f32x16;

#define N_NODES 8192
#define D_IN    256
#define D_OUT   128
#define LOG2E   1.44269504088896f

__device__ __forceinline__ unsigned short bf16_rne(float f) {
  unsigned int u = __float_as_uint(f);
  u += 0x7fffu + ((u >> 16) & 1u);
  return (unsigned short)(u >> 16);
}
__device__ __forceinline__ float bf16_to_f(unsigned short s) {
  return __uint_as_float(((unsigned int)s) << 16);
}

// ---------------- k0a: split x (fp32) -> x_hi, x_lo (bf16) ----------------
__global__ __launch_bounds__(256) void k_split_x(const float* __restrict__ x,
                                                 unsigned short* __restrict__ xhi,
                                                 unsigned short* __restrict__ xlo) {
  int idx = (blockIdx.x * 256 + threadIdx.x) * 8;
  float4 v0 = *(const float4*)(x + idx);
  float4 v1 = *(const float4*)(x + idx + 4);
  float v[8] = {v0.x, v0.y, v0.z, v0.w, v1.x, v1.y, v1.z, v1.w};
  unsigned int hw[4], lw[4];
#pragma unroll
  for (int p = 0; p < 4; ++p) {
    unsigned short h0 = bf16_rne(v[2 * p]);
    unsigned short h1 = bf16_rne(v[2 * p + 1]);
    unsigned short l0 = bf16_rne(v[2 * p] - bf16_to_f(h0));
    unsigned short l1 = bf16_rne(v[2 * p + 1] - bf16_to_f(h1));
    hw[p] = (unsigned int)h0 | ((unsigned int)h1 << 16);
    lw[p] = (unsigned int)l0 | ((unsigned int)l1 << 16);
  }
  *(uint4*)(xhi + idx) = make_uint4(hw[0], hw[1], hw[2], hw[3]);
  *(uint4*)(xlo + idx) = make_uint4(lw[0], lw[1], lw[2], lw[3]);
}

// ------------- k0b: split + transpose W -> W_hiT, W_loT [128][256] -------------
__global__ __launch_bounds__(256) void k_split_w(const float* __restrict__ W,
                                                 unsigned short* __restrict__ whiT,
                                                 unsigned short* __restrict__ wloT) {
  int c = blockIdx.x;
  int k = threadIdx.x;
  float v = W[k * D_OUT + c];
  unsigned short h = bf16_rne(v);
  unsigned short l = bf16_rne(v - bf16_to_f(h));
  whiT[c * D_IN + k] = h;
  wloT[c * D_IN + k] = l;
}

// ---- k1: h = x @ W (split-bf16 MFMA) + fused src/dst dots + B-panel pack ----
__global__ __launch_bounds__(256) void k_h_gemm(const unsigned short* __restrict__ xhi,
                                                const unsigned short* __restrict__ xlo,
                                                const unsigned short* __restrict__ whiT,
                                                const unsigned short* __restrict__ wloT,
                                                const float* __restrict__ a_src,
                                                const float* __restrict__ a_dst,
                                                float* __restrict__ srcv,
                                                float* __restrict__ dstv,
                                                unsigned short* __restrict__ phi,
                                                unsigned short* __restrict__ plo) {
  __shared__ float h_s[32][128];
  const int t = threadIdx.x, l = t & 63, wv = t >> 6;
  const int i0 = blockIdx.x * 32;
  const int m = wv >> 1, nh = wv & 1;
  const int frow = l & 15, kq = l >> 4;
  const size_t arow = (size_t)(i0 + m * 16 + frow);
  const unsigned short* pah = xhi + arow * D_IN + kq * 8;
  const unsigned short* pal = xlo + arow * D_IN + kq * 8;
  f32x4 acc[4];
#pragma unroll
  for (int nf = 0; nf < 4; ++nf) acc[nf] = (f32x4){0.f, 0.f, 0.f, 0.f};
#pragma unroll
  for (int kk = 0; kk < 8; ++kk) {
    const int k0 = kk * 32;
    bf16x8 ah = *(const bf16x8*)(pah + k0);
    bf16x8 al = *(const bf16x8*)(pal + k0);
#pragma unroll
    for (int nf = 0; nf < 4; ++nf) {
      const int col = nh * 64 + nf * 16 + frow;
      bf16x8 bh = *(const bf16x8*)(whiT + (size_t)col * D_IN + k0 + kq * 8);
      bf16x8 bl = *(const bf16x8*)(wloT + (size_t)col * D_IN + k0 + kq * 8);
      acc[nf] = __builtin_amdgcn_mfma_f32_16x16x32_bf16(ah, bh, acc[nf], 0, 0, 0);
      acc[nf] = __builtin_amdgcn_mfma_f32_16x16x32_bf16(al, bh, acc[nf], 0, 0, 0);
      acc[nf] = __builtin_amdgcn_mfma_f32_16x16x32_bf16(ah, bl, acc[nf], 0, 0, 0);
    }
  }
#pragma unroll
  for (int nf = 0; nf < 4; ++nf)
#pragma unroll
    for (int r = 0; r < 4; ++r)
      h_s[m * 16 + kq * 4 + r][nh * 64 + nf * 16 + frow] = acc[nf][r];
  __syncthreads();

  if (t < 32) {
    float s = 0.f, d = 0.f;
#pragma unroll
    for (int c = 0; c < D_OUT; ++c) {
      float v = h_s[t][c];
      s += v * a_src[c];
      d += v * a_dst[c];
    }
    srcv[i0 + t] = s * LOG2E;
    dstv[i0 + t] = d * LOG2E;
  }

  {
    const int b = t >> 7, ct = (t >> 5) & 3, lw = t & 31;
    const size_t kg = (size_t)(i0 / 16 + b);
#pragma unroll
    for (int half = 0; half < 2; ++half) {
      const int lane = lw + 32 * half;
      unsigned int hw[4], lwd[4];
#pragma unroll
      for (int p = 0; p < 4; ++p) {
        float v0 = h_s[b * 16 + half * 8 + 2 * p][ct * 32 + lw];
        float v1 = h_s[b * 16 + half * 8 + 2 * p + 1][ct * 32 + lw];
        unsigned short h0 = bf16_rne(v0), h1 = bf16_rne(v1);
        unsigned short l0 = bf16_rne(v0 - bf16_to_f(h0));
        unsigned short l1 = bf16_rne(v1 - bf16_to_f(h1));
        hw[p] = (unsigned int)h0 | ((unsigned int)h1 << 16);
        lwd[p] = (unsigned int)l0 | ((unsigned int)l1 << 16);
      }
      const size_t off = ((kg * 4 + ct) * 64 + lane) * 8;
      *(uint4*)(phi + off) = make_uint4(hw[0], hw[1], hw[2], hw[3]);
      *(uint4*)(plo + off) = make_uint4(lwd[0], lwd[1], lwd[2], lwd[3]);
    }
  }
}

// ---------------- k2: adj (int32) -> bitmask (1 bit/edge, 8 MB) ----------------
// grid 2048 x 256 (4 waves/block). Wave wv handles row blockIdx*4+wv.
// Per step: lane l loads adj[row][s*64+l] (256 B coalesced), ballot packs 64 bits,
// lane 0 stores the word. Pure HBM stream -> expect ~5.5-6 TB/s (the roofline pass).
__global__ __launch_bounds__(256) void k_mask(const int* __restrict__ adj,
                                              unsigned long long* __restrict__ maskw) {
  const int t = threadIdx.x, l = t & 63, wv = t >> 6;
  const int row = blockIdx.x * 4 + wv;
  const int* ap = adj + (size_t)row * N_NODES + l;
  unsigned long long* mp = maskw + (size_t)row * 128;
#pragma unroll 4
  for (int s = 0; s < 128; ++s) {
    int a = __builtin_nontemporal_load(ap + s * 64);
    unsigned long long b = __ballot(a > 0);
    if (l == 0) mp[s] = b;
  }
}

// ---------------- k3: fused masked-softmax aggregation (cache-resident v6) ----------------
// grid 256 (one 32-row tile per block = 1 block/CU), 1024 threads = 16 waves:
//   ch = wv>>3 (64-col half), js = wv&7 (j-slice). Per wave-iter: 32 j, 32 iters.
// All loop loads are L2/L3-class: mask word (8B), 8 coalesced B-frags, dstv from LDS.
// A-frag (32x32x16): lane (r32=l&31, kh=l>>5) -> A[r32][kh*8+e], j = jq + ks*16 + kh*8 + e.
__global__ __launch_bounds__(1024) void k_gat(const unsigned long long* __restrict__ maskw,
                                              const float* __restrict__ srcv,
                                              const float* __restrict__ dstv,
                                              const unsigned short* __restrict__ phi,
                                              const unsigned short* __restrict__ plo,
                                              float* __restrict__ out) {
  __shared__ float dstv_s[8192];   // 32 KB
  __shared__ float red[2][2048];   // 16 KB js-reduction buffer
  __shared__ float rsl[8][32];

  const int t = threadIdx.x, l = t & 63, wv = t >> 6;
  const int ch = wv >> 3, js = wv & 7;
  const int i0 = blockIdx.x * 32;
  const int r32 = l & 31, kh = l >> 5;

  ((float4*)dstv_s)[t] = ((const float4*)dstv)[t];
  ((float4*)dstv_s)[t + 1024] = ((const float4*)dstv)[t + 1024];
  const float s2 = srcv[i0 + r32];
  __syncthreads();

  // mask: word (js>>1) + it*4 of row i0+r32; lane's bits at (js&1)*32 + kh*8 (+16 for ks=1)
  const unsigned long long* mrow = maskw + (size_t)(i0 + r32) * 128 + (js >> 1);
  const int shl = (js & 1) * 32 + kh * 8;

  // panel bases: fragment (kst = js*2 + it*16 + ks, ct = ch*2 + cc) at ((kst*4+ct)*64+l)*8
  const unsigned short* pb0 = phi + ((size_t)((js * 2) * 4 + ch * 2) * 64 + l) * 8;
  const unsigned short* pb1 = plo + ((size_t)((js * 2) * 4 + ch * 2) * 64 + l) * 8;
  // strides (ushorts): it: 32768, ks: 2048, ct: 512

  f32x16 acc0, acc1;
#pragma unroll
  for (int q = 0; q < 16; ++q) { acc0[q] = 0.f; acc1[q] = 0.f; }
  float rs = 0.f;

  for (int it = 0; it < 32; ++it) {
    // loads first: 1 mask word + 8 B-frags (all L2/L3); compute below gives slack
    unsigned long long mw = mrow[it * 4];
    const unsigned short* pa = pb0 + it * 32768;
    const unsigned short* pc = pb1 + it * 32768;
    bf16x8 bh00 = *(const bf16x8*)(pa);
    bf16x8 bl00 = *(const bf16x8*)(pc);
    bf16x8 bh01 = *(const bf16x8*)(pa + 512);
    bf16x8 bl01 = *(const bf16x8*)(pc + 512);
    bf16x8 bh10 = *(const bf16x8*)(pa + 2048);
    bf16x8 bl10 = *(const bf16x8*)(pc + 2048);
    bf16x8 bh11 = *(const bf16x8*)(pa + 2048 + 512);
    bf16x8 bl11 = *(const bf16x8*)(pc + 2048 + 512);

    const int jl = it * 256 + js * 32 + kh * 8;
    const unsigned int u0 = (unsigned int)(mw >> shl) & 0xFFu;
    const unsigned int u1 = (unsigned int)(mw >> (shl + 16)) & 0xFFu;

#pragma unroll
    for (int ks = 0; ks < 2; ++ks) {
      f32x4 dva = *(const f32x4*)&dstv_s[jl + ks * 16];
      f32x4 dvb = *(const f32x4*)&dstv_s[jl + ks * 16 + 4];
      const unsigned int u = ks ? u1 : u0;
      float w[8];
#pragma unroll
      for (int e = 0; e < 4; ++e) {
        float e0 = s2 + dva[e]; e0 = fmaxf(e0, 0.2f * e0);
        float e1 = s2 + dvb[e]; e1 = fmaxf(e1, 0.2f * e1);
        w[e]     = ((u >> e) & 1u)       ? exp2f(e0) : 0.f;
        w[4 + e] = ((u >> (4 + e)) & 1u) ? exp2f(e1) : 0.f;
      }
      if (ch == 0)
        rs += ((w[0] + w[1]) + (w[2] + w[3])) + ((w[4] + w[5]) + (w[6] + w[7]));
      union { bf16x8 v; unsigned int u4[4]; } af;
#pragma unroll
      for (int p = 0; p < 4; ++p)
        af.u4[p] = (unsigned int)bf16_rne(w[2 * p]) | ((unsigned int)bf16_rne(w[2 * p + 1]) << 16);

      if (ks == 0) {
        acc0 = __builtin_amdgcn_mfma_f32_32x32x16_bf16(af.v, bh00, acc0, 0, 0, 0);
        acc0 = __builtin_amdgcn_mfma_f32_32x32x16_bf16(af.v, bl00, acc0, 0, 0, 0);
        acc1 = __builtin_amdgcn_mfma_f32_32x32x16_bf16(af.v, bh01, acc1, 0, 0, 0);
        acc1 = __builtin_amdgcn_mfma_f32_32x32x16_bf16(af.v, bl01, acc1, 0, 0, 0);
      } else {
        acc0 = __builtin_amdgcn_mfma_f32_32x32x16_bf16(af.v, bh10, acc0, 0, 0, 0);
        acc0 = __builtin_amdgcn_mfma_f32_32x32x16_bf16(af.v, bl10, acc0, 0, 0, 0);
        acc1 = __builtin_amdgcn_mfma_f32_32x32x16_bf16(af.v, bh11, acc1, 0, 0, 0);
        acc1 = __builtin_amdgcn_mfma_f32_32x32x16_bf16(af.v, bl11, acc1, 0, 0, 0);
      }
    }
  }

  // rowsum across kh halves; stash per js
  rs += __shfl_xor(rs, 32);
  if (ch == 0 && kh == 0) rsl[js][r32] = rs;

  // js-reduction of numerators: 7 serial rounds through 16 KB buffer
#pragma unroll
  for (int q = 1; q < 8; ++q) {
    if (js == q) {
#pragma unroll
      for (int reg = 0; reg < 16; ++reg) {
        red[ch][reg * 64 + l] = acc0[reg];
        red[ch][1024 + reg * 64 + l] = acc1[reg];
      }
    }
    __syncthreads();
    if (js == 0) {
#pragma unroll
      for (int reg = 0; reg < 16; ++reg) {
        acc0[reg] += red[ch][reg * 64 + l];
        acc1[reg] += red[ch][1024 + reg * 64 + l];
      }
    }
    __syncthreads();
  }

  if (js == 0) {
#pragma unroll
    for (int reg = 0; reg < 16; ++reg) {
      const int row = (reg & 3) + 8 * (reg >> 2) + 4 * kh;
      const float rsum = (((rsl[0][row] + rsl[1][row]) + (rsl[2][row] + rsl[3][row])) +
                          ((rsl[4][row] + rsl[5][row]) + (rsl[6][row] + rsl[7][row])));
      out[(size_t)(i0 + row) * D_OUT + ch * 64 + r32] = acc0[reg] / rsum;
      out[(size_t)(i0 + row) * D_OUT + ch * 64 + 32 + r32] = acc1[reg] / rsum;
    }
  }
}

extern "C" void kernel_launch(void* const* d_in, const int* in_sizes, int n_in,
                              void* d_out, int out_size, void* d_ws, size_t ws_size,
                              hipStream_t stream) {
  const float* x     = (const float*)d_in[0];
  const int*   adj   = (const int*)d_in[1];
  const float* W     = (const float*)d_in[2];
  const float* a_src = (const float*)d_in[3];
  const float* a_dst = (const float*)d_in[4];
  float* out = (float*)d_out;

  char* ws = (char*)d_ws;
  unsigned short* xhi  = (unsigned short*)(ws);                               // 4 MB (dead after k_h_gemm)
  unsigned short* xlo  = (unsigned short*)(ws + (4 << 20));                   // 4 MB (dead after k_h_gemm)
  unsigned short* whiT = (unsigned short*)(ws + (8 << 20));                   // 64 KB
  unsigned short* wloT = (unsigned short*)(ws + (8 << 20) + (64 << 10));      // 64 KB
  unsigned short* phi  = (unsigned short*)(ws + (8 << 20) + (128 << 10));     // 2 MB
  unsigned short* plo  = (unsigned short*)(ws + (10 << 20) + (128 << 10));    // 2 MB
  float*          srcv = (float*)(ws + (12 << 20) + (128 << 10));             // 32 KB
  float*          dstv = (float*)(ws + (12 << 20) + (160 << 10));             // 32 KB
  unsigned long long* maskw = (unsigned long long*)(ws);                      // 8 MB, aliases xhi/xlo

  k_split_x<<<dim3(1024), dim3(256), 0, stream>>>(x, xhi, xlo);
  k_split_w<<<dim3(128), dim3(256), 0, stream>>>(W, whiT, wloT);
  k_h_gemm<<<dim3(256), dim3(256), 0, stream>>>(xhi, xlo, whiT, wloT,
                                                a_src, a_dst, srcv, dstv, phi, plo);
  k_mask<<<dim3(2048), dim3(256), 0, stream>>>(adj, maskw);
  k_gat<<<dim3(256), dim3(1024), 0, stream>>>(maskw, srcv, dstv, phi, plo, out);
}

// Round 7
// 181.605 us; speedup vs baseline: 1.3938x; 1.0380x over previous
//
#include <hip/hip_runtime.h>

typedef __attribute__((ext_vector_type(8))) short bf16x8;
typedef __attribute__((ext_vector_type(4))) float f32x4;
typedef __attribute__((ext_vector_type(16))) float f32x16;

#define N_NODES 8192
#define D_IN    256
#define D_OUT   128
#define LOG2E   1.44269504088896f

__device__ __forceinline__ unsigned short bf16_rne(float f) {
  unsigned int u = __float_as_uint(f);
  u += 0x7fffu + ((u >> 16) & 1u);
  return (unsigned short)(u >> 16);
}
__device__ __forceinline__ float bf16_to_f(unsigned short s) {
  return __uint_as_float(((unsigned int)s) << 16);
}

// ---------------- k0a: split x (fp32) -> x_hi, x_lo (bf16) ----------------
__global__ __launch_bounds__(256) void k_split_x(const float* __restrict__ x,
                                                 unsigned short* __restrict__ xhi,
                                                 unsigned short* __restrict__ xlo) {
  int idx = (blockIdx.x * 256 + threadIdx.x) * 8;
  float4 v0 = *(const float4*)(x + idx);
  float4 v1 = *(const float4*)(x + idx + 4);
  float v[8] = {v0.x, v0.y, v0.z, v0.w, v1.x, v1.y, v1.z, v1.w};
  unsigned int hw[4], lw[4];
#pragma unroll
  for (int p = 0; p < 4; ++p) {
    unsigned short h0 = bf16_rne(v[2 * p]);
    unsigned short h1 = bf16_rne(v[2 * p + 1]);
    unsigned short l0 = bf16_rne(v[2 * p] - bf16_to_f(h0));
    unsigned short l1 = bf16_rne(v[2 * p + 1] - bf16_to_f(h1));
    hw[p] = (unsigned int)h0 | ((unsigned int)h1 << 16);
    lw[p] = (unsigned int)l0 | ((unsigned int)l1 << 16);
  }
  *(uint4*)(xhi + idx) = make_uint4(hw[0], hw[1], hw[2], hw[3]);
  *(uint4*)(xlo + idx) = make_uint4(lw[0], lw[1], lw[2], lw[3]);
}

// ------------- k0b: split + transpose W -> W_hiT, W_loT [128][256] -------------
__global__ __launch_bounds__(256) void k_split_w(const float* __restrict__ W,
                                                 unsigned short* __restrict__ whiT,
                                                 unsigned short* __restrict__ wloT) {
  int c = blockIdx.x;
  int k = threadIdx.x;
  float v = W[k * D_OUT + c];
  unsigned short h = bf16_rne(v);
  unsigned short l = bf16_rne(v - bf16_to_f(h));
  whiT[c * D_IN + k] = h;
  wloT[c * D_IN + k] = l;
}

// ---- k1: h = x @ W (split-bf16 MFMA) + fused src/dst dots + B-panel pack ----
// Panels (hi only) for mfma_f32_32x32x16_bf16 B-frags: fragment (kstep kg, ct):
//   element (lane l, e) = bf16(h[kg*16 + (l>>5)*8 + e][ct*32 + (l&31)])
//   at phi[((kg*4 + ct)*64 + l)*8 + e] -> wave load at base + l*16B coalesced.
__global__ __launch_bounds__(256) void k_h_gemm(const unsigned short* __restrict__ xhi,
                                                const unsigned short* __restrict__ xlo,
                                                const unsigned short* __restrict__ whiT,
                                                const unsigned short* __restrict__ wloT,
                                                const float* __restrict__ a_src,
                                                const float* __restrict__ a_dst,
                                                float* __restrict__ srcv,
                                                float* __restrict__ dstv,
                                                unsigned short* __restrict__ phi) {
  __shared__ float h_s[32][128];
  const int t = threadIdx.x, l = t & 63, wv = t >> 6;
  const int i0 = blockIdx.x * 32;
  const int m = wv >> 1, nh = wv & 1;
  const int frow = l & 15, kq = l >> 4;
  const size_t arow = (size_t)(i0 + m * 16 + frow);
  const unsigned short* pah = xhi + arow * D_IN + kq * 8;
  const unsigned short* pal = xlo + arow * D_IN + kq * 8;
  f32x4 acc[4];
#pragma unroll
  for (int nf = 0; nf < 4; ++nf) acc[nf] = (f32x4){0.f, 0.f, 0.f, 0.f};
#pragma unroll
  for (int kk = 0; kk < 8; ++kk) {
    const int k0 = kk * 32;
    bf16x8 ah = *(const bf16x8*)(pah + k0);
    bf16x8 al = *(const bf16x8*)(pal + k0);
#pragma unroll
    for (int nf = 0; nf < 4; ++nf) {
      const int col = nh * 64 + nf * 16 + frow;
      bf16x8 bh = *(const bf16x8*)(whiT + (size_t)col * D_IN + k0 + kq * 8);
      bf16x8 bl = *(const bf16x8*)(wloT + (size_t)col * D_IN + k0 + kq * 8);
      acc[nf] = __builtin_amdgcn_mfma_f32_16x16x32_bf16(ah, bh, acc[nf], 0, 0, 0);
      acc[nf] = __builtin_amdgcn_mfma_f32_16x16x32_bf16(al, bh, acc[nf], 0, 0, 0);
      acc[nf] = __builtin_amdgcn_mfma_f32_16x16x32_bf16(ah, bl, acc[nf], 0, 0, 0);
    }
  }
#pragma unroll
  for (int nf = 0; nf < 4; ++nf)
#pragma unroll
    for (int r = 0; r < 4; ++r)
      h_s[m * 16 + kq * 4 + r][nh * 64 + nf * 16 + frow] = acc[nf][r];
  __syncthreads();

  if (t < 32) {
    float s = 0.f, d = 0.f;
#pragma unroll
    for (int c = 0; c < D_OUT; ++c) {
      float v = h_s[t][c];
      s += v * a_src[c];
      d += v * a_dst[c];
    }
    srcv[i0 + t] = s * LOG2E;
    dstv[i0 + t] = d * LOG2E;
  }

  {
    const int b = t >> 7, ct = (t >> 5) & 3, lw = t & 31;
    const size_t kg = (size_t)(i0 / 16 + b);
#pragma unroll
    for (int half = 0; half < 2; ++half) {
      const int lane = lw + 32 * half;
      unsigned int hw[4];
#pragma unroll
      for (int p = 0; p < 4; ++p) {
        float v0 = h_s[b * 16 + half * 8 + 2 * p][ct * 32 + lw];
        float v1 = h_s[b * 16 + half * 8 + 2 * p + 1][ct * 32 + lw];
        hw[p] = (unsigned int)bf16_rne(v0) | ((unsigned int)bf16_rne(v1) << 16);
      }
      const size_t off = ((kg * 4 + ct) * 64 + lane) * 8;
      *(uint4*)(phi + off) = make_uint4(hw[0], hw[1], hw[2], hw[3]);
    }
  }
}

// ---------------- k2: adj (int32) -> bitmask (1 bit/edge, 8 MB) ----------------
__global__ __launch_bounds__(256) void k_mask(const int* __restrict__ adj,
                                              unsigned long long* __restrict__ maskw) {
  const int t = threadIdx.x, l = t & 63, wv = t >> 6;
  const int row = blockIdx.x * 4 + wv;
  const int* ap = adj + (size_t)row * N_NODES + l;
  unsigned long long* mp = maskw + (size_t)row * 128;
#pragma unroll 4
  for (int s = 0; s < 128; ++s) {
    int a = __builtin_nontemporal_load(ap + s * 64);
    unsigned long long b = __ballot(a > 0);
    if (l == 0) mp[s] = b;
  }
}

// ---------------- k3: fused masked-softmax aggregation (v7) ----------------
// grid 256 (32-row tile / block), 1024 threads = 16 waves: ch = wv>>3, js = wv&7.
// Mask staged to LDS transposed+padded: mask_s[w][r], in-loop ds_read_b64 is a
// 2-way-broadcast conflict-free read. B panels hi-only: 4 frags / 4 MFMA per iter.
__global__ __launch_bounds__(1024) void k_gat(const unsigned long long* __restrict__ maskw,
                                              const float* __restrict__ srcv,
                                              const float* __restrict__ dstv,
                                              const unsigned short* __restrict__ phi,
                                              float* __restrict__ out) {
  __shared__ unsigned long long mask_s[128][33];  // 33.8 KB, padded
  __shared__ float dstv_s[8192];                  // 32 KB
  __shared__ float red[2][2048];                  // 16 KB js-reduction buffer
  __shared__ float rsl[8][32];

  const int t = threadIdx.x, l = t & 63, wv = t >> 6;
  const int ch = wv >> 3, js = wv & 7;
  const int i0 = blockIdx.x * 32;
  const int r32 = l & 31, kh = l >> 5;

  // stage dstv + transposed mask (coalesced global reads)
  ((float4*)dstv_s)[t] = ((const float4*)dstv)[t];
  ((float4*)dstv_s)[t + 1024] = ((const float4*)dstv)[t + 1024];
#pragma unroll
  for (int q = 0; q < 4; ++q) {
    const int idx = q * 1024 + t;
    const int r = idx >> 7, w = idx & 127;
    mask_s[w][r] = maskw[(size_t)(i0 + r) * 128 + w];
  }
  const float s2 = srcv[i0 + r32];
  __syncthreads();

  const int shl = (js & 1) * 32 + kh * 8;
  const int w0 = js >> 1;
  const unsigned short* pb0 = phi + ((size_t)((js * 2) * 4 + ch * 2) * 64 + l) * 8;
  // strides (ushorts): it: 32768, ks: 2048, ct: 512

  f32x16 acc0, acc1;
#pragma unroll
  for (int q = 0; q < 16; ++q) { acc0[q] = 0.f; acc1[q] = 0.f; }
  float rs = 0.f;

  for (int it = 0; it < 32; ++it) {
    const unsigned long long mw = mask_s[w0 + it * 4][r32];
    const unsigned short* pa = pb0 + it * 32768;
    bf16x8 bh00 = *(const bf16x8*)(pa);
    bf16x8 bh01 = *(const bf16x8*)(pa + 512);
    bf16x8 bh10 = *(const bf16x8*)(pa + 2048);
    bf16x8 bh11 = *(const bf16x8*)(pa + 2048 + 512);

    const int jl = it * 256 + js * 32 + kh * 8;
    const unsigned int u0 = (unsigned int)(mw >> shl) & 0xFFu;
    const unsigned int u1 = (unsigned int)(mw >> (shl + 16)) & 0xFFu;

#pragma unroll
    for (int ks = 0; ks < 2; ++ks) {
      f32x4 dva = *(const f32x4*)&dstv_s[jl + ks * 16];
      f32x4 dvb = *(const f32x4*)&dstv_s[jl + ks * 16 + 4];
      const unsigned int u = ks ? u1 : u0;
      float w[8];
#pragma unroll
      for (int e = 0; e < 4; ++e) {
        float e0 = s2 + dva[e]; e0 = fmaxf(e0, 0.2f * e0);
        float e1 = s2 + dvb[e]; e1 = fmaxf(e1, 0.2f * e1);
        w[e]     = ((u >> e) & 1u)       ? exp2f(e0) : 0.f;
        w[4 + e] = ((u >> (4 + e)) & 1u) ? exp2f(e1) : 0.f;
      }
      if (ch == 0)
        rs += ((w[0] + w[1]) + (w[2] + w[3])) + ((w[4] + w[5]) + (w[6] + w[7]));
      union { bf16x8 v; unsigned int u4[4]; } af;
#pragma unroll
      for (int p = 0; p < 4; ++p)
        af.u4[p] = (unsigned int)bf16_rne(w[2 * p]) | ((unsigned int)bf16_rne(w[2 * p + 1]) << 16);

      if (ks == 0) {
        acc0 = __builtin_amdgcn_mfma_f32_32x32x16_bf16(af.v, bh00, acc0, 0, 0, 0);
        acc1 = __builtin_amdgcn_mfma_f32_32x32x16_bf16(af.v, bh01, acc1, 0, 0, 0);
      } else {
        acc0 = __builtin_amdgcn_mfma_f32_32x32x16_bf16(af.v, bh10, acc0, 0, 0, 0);
        acc1 = __builtin_amdgcn_mfma_f32_32x32x16_bf16(af.v, bh11, acc1, 0, 0, 0);
      }
    }
  }

  // rowsum across kh halves; stash per js
  rs += __shfl_xor(rs, 32);
  if (ch == 0 && kh == 0) rsl[js][r32] = rs;

  // js-reduction of numerators: 7 serial rounds through 16 KB buffer
#pragma unroll
  for (int q = 1; q < 8; ++q) {
    if (js == q) {
#pragma unroll
      for (int reg = 0; reg < 16; ++reg) {
        red[ch][reg * 64 + l] = acc0[reg];
        red[ch][1024 + reg * 64 + l] = acc1[reg];
      }
    }
    __syncthreads();
    if (js == 0) {
#pragma unroll
      for (int reg = 0; reg < 16; ++reg) {
        acc0[reg] += red[ch][reg * 64 + l];
        acc1[reg] += red[ch][1024 + reg * 64 + l];
      }
    }
    __syncthreads();
  }

  if (js == 0) {
#pragma unroll
    for (int reg = 0; reg < 16; ++reg) {
      const int row = (reg & 3) + 8 * (reg >> 2) + 4 * kh;
      const float rsum = (((rsl[0][row] + rsl[1][row]) + (rsl[2][row] + rsl[3][row])) +
                          ((rsl[4][row] + rsl[5][row]) + (rsl[6][row] + rsl[7][row])));
      out[(size_t)(i0 + row) * D_OUT + ch * 64 + r32] = acc0[reg] / rsum;
      out[(size_t)(i0 + row) * D_OUT + ch * 64 + 32 + r32] = acc1[reg] / rsum;
    }
  }
}

extern "C" void kernel_launch(void* const* d_in, const int* in_sizes, int n_in,
                              void* d_out, int out_size, void* d_ws, size_t ws_size,
                              hipStream_t stream) {
  const float* x     = (const float*)d_in[0];
  const int*   adj   = (const int*)d_in[1];
  const float* W     = (const float*)d_in[2];
  const float* a_src = (const float*)d_in[3];
  const float* a_dst = (const float*)d_in[4];
  float* out = (float*)d_out;

  char* ws = (char*)d_ws;
  unsigned short* xhi  = (unsigned short*)(ws);                               // 4 MB (dead after k_h_gemm)
  unsigned short* xlo  = (unsigned short*)(ws + (4 << 20));                   // 4 MB (dead after k_h_gemm)
  unsigned short* whiT = (unsigned short*)(ws + (8 << 20));                   // 64 KB
  unsigned short* wloT = (unsigned short*)(ws + (8 << 20) + (64 << 10));      // 64 KB
  unsigned short* phi  = (unsigned short*)(ws + (8 << 20) + (128 << 10));     // 2 MB
  float*          srcv = (float*)(ws + (12 << 20) + (128 << 10));             // 32 KB
  float*          dstv = (float*)(ws + (12 << 20) + (160 << 10));             // 32 KB
  unsigned long long* maskw = (unsigned long long*)(ws);                      // 8 MB, aliases xhi/xlo

  k_split_x<<<dim3(1024), dim3(256), 0, stream>>>(x, xhi, xlo);
  k_split_w<<<dim3(128), dim3(256), 0, stream>>>(W, whiT, wloT);
  k_h_gemm<<<dim3(256), dim3(256), 0, stream>>>(xhi, xlo, whiT, wloT,
                                                a_src, a_dst, srcv, dstv, phi);
  k_mask<<<dim3(2048), dim3(256), 0, stream>>>(adj, maskw);
  k_gat<<<dim3(256), dim3(1024), 0, stream>>>(maskw, srcv, dstv, phi, out);
}

// Round 8
// 176.528 us; speedup vs baseline: 1.4339x; 1.0288x over previous
//
#include <hip/hip_runtime.h>
#include <hip/hip_bf16.h>

typedef __attribute__((ext_vector_type(8))) short bf16x8;
typedef __attribute__((ext_vector_type(4))) float f32x4;
typedef __attribute__((ext_vector_type(16))) float f32x16;

#define N_NODES 8192
#define D_IN    256
#define D_OUT   128
#define LOG2E   1.44269504088896f

__device__ __forceinline__ unsigned short bf16_rne(float f) {
  unsigned int u = __float_as_uint(f);
  u += 0x7fffu + ((u >> 16) & 1u);
  return (unsigned short)(u >> 16);
}
__device__ __forceinline__ float bf16_to_f(unsigned short s) {
  return __uint_as_float(((unsigned int)s) << 16);
}
__device__ __forceinline__ unsigned int pack_bf16x2(float lo, float hi) {
  __hip_bfloat162 b2 = __float22bfloat162_rn(make_float2(lo, hi));
  union { __hip_bfloat162 b; unsigned int u; } cv;
  cv.b = b2;
  return cv.u;
}

// ---------------- k_mask: adj (int32) -> bitmask (1 bit/edge, 8 MB) ----------------
// Runs FIRST (depends only on adj) so later kernels' outputs stay L2/L3-hot for k_gat.
__global__ __launch_bounds__(256) void k_mask(const int* __restrict__ adj,
                                              unsigned long long* __restrict__ maskw) {
  const int t = threadIdx.x, l = t & 63, wv = t >> 6;
  const int row = blockIdx.x * 4 + wv;
  const int* ap = adj + (size_t)row * N_NODES + l;
  unsigned long long* mp = maskw + (size_t)row * 128;
#pragma unroll 8
  for (int s = 0; s < 128; ++s) {
    int a = __builtin_nontemporal_load(ap + s * 64);
    unsigned long long b = __ballot(a > 0);
    if (l == 0) mp[s] = b;
  }
}

// ---------------- k0a: split x (fp32) -> x_hi, x_lo (bf16) ----------------
__global__ __launch_bounds__(256) void k_split_x(const float* __restrict__ x,
                                                 unsigned short* __restrict__ xhi,
                                                 unsigned short* __restrict__ xlo) {
  int idx = (blockIdx.x * 256 + threadIdx.x) * 8;
  float4 v0 = *(const float4*)(x + idx);
  float4 v1 = *(const float4*)(x + idx + 4);
  float v[8] = {v0.x, v0.y, v0.z, v0.w, v1.x, v1.y, v1.z, v1.w};
  unsigned int hw[4], lw[4];
#pragma unroll
  for (int p = 0; p < 4; ++p) {
    unsigned short h0 = bf16_rne(v[2 * p]);
    unsigned short h1 = bf16_rne(v[2 * p + 1]);
    unsigned short l0 = bf16_rne(v[2 * p] - bf16_to_f(h0));
    unsigned short l1 = bf16_rne(v[2 * p + 1] - bf16_to_f(h1));
    hw[p] = (unsigned int)h0 | ((unsigned int)h1 << 16);
    lw[p] = (unsigned int)l0 | ((unsigned int)l1 << 16);
  }
  *(uint4*)(xhi + idx) = make_uint4(hw[0], hw[1], hw[2], hw[3]);
  *(uint4*)(xlo + idx) = make_uint4(lw[0], lw[1], lw[2], lw[3]);
}

// ------------- k0b: split + transpose W -> W_hiT, W_loT [128][256] -------------
__global__ __launch_bounds__(256) void k_split_w(const float* __restrict__ W,
                                                 unsigned short* __restrict__ whiT,
                                                 unsigned short* __restrict__ wloT) {
  int c = blockIdx.x;
  int k = threadIdx.x;
  float v = W[k * D_OUT + c];
  unsigned short h = bf16_rne(v);
  unsigned short l = bf16_rne(v - bf16_to_f(h));
  whiT[c * D_IN + k] = h;
  wloT[c * D_IN + k] = l;
}

// ---- k1: h = x @ W (split-bf16 MFMA) + fused src/dst dots + B-panel pack ----
// Panels (hi only) for mfma_f32_32x32x16_bf16 B-frags: fragment (kstep kg, ct):
//   element (lane l, e) = bf16(h[kg*16 + (l>>5)*8 + e][ct*32 + (l&31)])
//   at phi[((kg*4 + ct)*64 + l)*8 + e] -> wave load at base + l*16B coalesced.
__global__ __launch_bounds__(256) void k_h_gemm(const unsigned short* __restrict__ xhi,
                                                const unsigned short* __restrict__ xlo,
                                                const unsigned short* __restrict__ whiT,
                                                const unsigned short* __restrict__ wloT,
                                                const float* __restrict__ a_src,
                                                const float* __restrict__ a_dst,
                                                float* __restrict__ srcv,
                                                float* __restrict__ dstv,
                                                unsigned short* __restrict__ phi) {
  __shared__ float h_s[32][128];
  const int t = threadIdx.x, l = t & 63, wv = t >> 6;
  const int i0 = blockIdx.x * 32;
  const int m = wv >> 1, nh = wv & 1;
  const int frow = l & 15, kq = l >> 4;
  const size_t arow = (size_t)(i0 + m * 16 + frow);
  const unsigned short* pah = xhi + arow * D_IN + kq * 8;
  const unsigned short* pal = xlo + arow * D_IN + kq * 8;
  f32x4 acc[4];
#pragma unroll
  for (int nf = 0; nf < 4; ++nf) acc[nf] = (f32x4){0.f, 0.f, 0.f, 0.f};
#pragma unroll
  for (int kk = 0; kk < 8; ++kk) {
    const int k0 = kk * 32;
    bf16x8 ah = *(const bf16x8*)(pah + k0);
    bf16x8 al = *(const bf16x8*)(pal + k0);
#pragma unroll
    for (int nf = 0; nf < 4; ++nf) {
      const int col = nh * 64 + nf * 16 + frow;
      bf16x8 bh = *(const bf16x8*)(whiT + (size_t)col * D_IN + k0 + kq * 8);
      bf16x8 bl = *(const bf16x8*)(wloT + (size_t)col * D_IN + k0 + kq * 8);
      acc[nf] = __builtin_amdgcn_mfma_f32_16x16x32_bf16(ah, bh, acc[nf], 0, 0, 0);
      acc[nf] = __builtin_amdgcn_mfma_f32_16x16x32_bf16(al, bh, acc[nf], 0, 0, 0);
      acc[nf] = __builtin_amdgcn_mfma_f32_16x16x32_bf16(ah, bl, acc[nf], 0, 0, 0);
    }
  }
#pragma unroll
  for (int nf = 0; nf < 4; ++nf)
#pragma unroll
    for (int r = 0; r < 4; ++r)
      h_s[m * 16 + kq * 4 + r][nh * 64 + nf * 16 + frow] = acc[nf][r];
  __syncthreads();

  if (t < 32) {
    float s = 0.f, d = 0.f;
#pragma unroll
    for (int c = 0; c < D_OUT; ++c) {
      float v = h_s[t][c];
      s += v * a_src[c];
      d += v * a_dst[c];
    }
    srcv[i0 + t] = s * LOG2E;
    dstv[i0 + t] = d * LOG2E;
  }

  {
    const int b = t >> 7, ct = (t >> 5) & 3, lw = t & 31;
    const size_t kg = (size_t)(i0 / 16 + b);
#pragma unroll
    for (int half = 0; half < 2; ++half) {
      const int lane = lw + 32 * half;
      unsigned int hw[4];
#pragma unroll
      for (int p = 0; p < 4; ++p) {
        float v0 = h_s[b * 16 + half * 8 + 2 * p][ct * 32 + lw];
        float v1 = h_s[b * 16 + half * 8 + 2 * p + 1][ct * 32 + lw];
        hw[p] = (unsigned int)bf16_rne(v0) | ((unsigned int)bf16_rne(v1) << 16);
      }
      const size_t off = ((kg * 4 + ct) * 64 + lane) * 8;
      *(uint4*)(phi + off) = make_uint4(hw[0], hw[1], hw[2], hw[3]);
    }
  }
}

// ---------------- k3: fused masked-softmax aggregation (v8: reg double-buffer) ----------------
// grid 256 (32-row tile / block), 1024 threads = 16 waves: ch = wv>>3, js = wv&7.
// Per iter: prefetch it+1's mask word + 4 B-frags into NAMED registers, pinned with
// sched_barrier(0) so they cannot sink; then compute w(it) + 4 MFMA from the
// previous prefetch. Load->use distance = one full iteration of VALU work.
__global__ __launch_bounds__(1024) void k_gat(const unsigned long long* __restrict__ maskw,
                                              const float* __restrict__ srcv,
                                              const float* __restrict__ dstv,
                                              const unsigned short* __restrict__ phi,
                                              float* __restrict__ out) {
  __shared__ unsigned long long mask_s[128][33];  // 33.8 KB, padded
  __shared__ float dstv_s[8192];                  // 32 KB
  __shared__ float red[2][2048];                  // 16 KB js-reduction buffer
  __shared__ float rsl[8][32];

  const int t = threadIdx.x, l = t & 63, wv = t >> 6;
  const int ch = wv >> 3, js = wv & 7;
  const int i0 = blockIdx.x * 32;
  const int r32 = l & 31, kh = l >> 5;

  // stage dstv + transposed mask (coalesced global reads)
  ((float4*)dstv_s)[t] = ((const float4*)dstv)[t];
  ((float4*)dstv_s)[t + 1024] = ((const float4*)dstv)[t + 1024];
#pragma unroll
  for (int q = 0; q < 4; ++q) {
    const int idx = q * 1024 + t;
    const int r = idx >> 7, w = idx & 127;
    mask_s[w][r] = maskw[(size_t)(i0 + r) * 128 + w];
  }
  const float s2 = srcv[i0 + r32];
  __syncthreads();

  const int shl = (js & 1) * 32 + kh * 8;
  const int w0 = js >> 1;
  const unsigned short* pb0 = phi + ((size_t)((js * 2) * 4 + ch * 2) * 64 + l) * 8;
  // strides (ushorts): it: 32768, ks: 2048, ct: 512

  f32x16 acc0, acc1;
#pragma unroll
  for (int q = 0; q < 16; ++q) { acc0[q] = 0.f; acc1[q] = 0.f; }
  float rs = 0.f;

  // ---- prologue: prefetch it = 0 ----
  unsigned long long mwA = mask_s[w0][r32];
  bf16x8 b00A = *(const bf16x8*)(pb0);
  bf16x8 b01A = *(const bf16x8*)(pb0 + 512);
  bf16x8 b10A = *(const bf16x8*)(pb0 + 2048);
  bf16x8 b11A = *(const bf16x8*)(pb0 + 2048 + 512);
  __builtin_amdgcn_sched_barrier(0);

  for (int it = 0; it < 32; ++it) {
    // 1) issue prefetch for it+1 (pinned: cannot sink below the barrier)
    const int itn = (it < 31) ? it + 1 : 31;
    const unsigned short* pan = pb0 + itn * 32768;
    unsigned long long mwB = mask_s[w0 + itn * 4][r32];
    bf16x8 b00B = *(const bf16x8*)(pan);
    bf16x8 b01B = *(const bf16x8*)(pan + 512);
    bf16x8 b10B = *(const bf16x8*)(pan + 2048);
    bf16x8 b11B = *(const bf16x8*)(pan + 2048 + 512);
    __builtin_amdgcn_sched_barrier(0);

    // 2) compute w(it) + MFMA(it) from the A-buffer
    const int jl = it * 256 + js * 32 + kh * 8;
    const unsigned int u0 = (unsigned int)(mwA >> shl) & 0xFFu;
    const unsigned int u1 = (unsigned int)(mwA >> (shl + 16)) & 0xFFu;

#pragma unroll
    for (int ks = 0; ks < 2; ++ks) {
      f32x4 dva = *(const f32x4*)&dstv_s[jl + ks * 16];
      f32x4 dvb = *(const f32x4*)&dstv_s[jl + ks * 16 + 4];
      const unsigned int u = ks ? u1 : u0;
      float w[8];
#pragma unroll
      for (int e = 0; e < 4; ++e) {
        float e0 = s2 + dva[e]; e0 = fmaxf(e0, 0.2f * e0);
        float e1 = s2 + dvb[e]; e1 = fmaxf(e1, 0.2f * e1);
        w[e]     = ((u >> e) & 1u)       ? exp2f(e0) : 0.f;
        w[4 + e] = ((u >> (4 + e)) & 1u) ? exp2f(e1) : 0.f;
      }
      if (ch == 0)
        rs += ((w[0] + w[1]) + (w[2] + w[3])) + ((w[4] + w[5]) + (w[6] + w[7]));
      union { bf16x8 v; unsigned int u4[4]; } af;
#pragma unroll
      for (int p = 0; p < 4; ++p)
        af.u4[p] = pack_bf16x2(w[2 * p], w[2 * p + 1]);

      if (ks == 0) {
        acc0 = __builtin_amdgcn_mfma_f32_32x32x16_bf16(af.v, b00A, acc0, 0, 0, 0);
        acc1 = __builtin_amdgcn_mfma_f32_32x32x16_bf16(af.v, b01A, acc1, 0, 0, 0);
      } else {
        acc0 = __builtin_amdgcn_mfma_f32_32x32x16_bf16(af.v, b10A, acc0, 0, 0, 0);
        acc1 = __builtin_amdgcn_mfma_f32_32x32x16_bf16(af.v, b11A, acc1, 0, 0, 0);
      }
    }

    // 3) rotate buffers
    mwA = mwB;
    b00A = b00B; b01A = b01B; b10A = b10B; b11A = b11B;
  }

  // rowsum across kh halves; stash per js
  rs += __shfl_xor(rs, 32);
  if (ch == 0 && kh == 0) rsl[js][r32] = rs;

  // js-reduction of numerators: 7 serial rounds through 16 KB buffer
#pragma unroll
  for (int q = 1; q < 8; ++q) {
    if (js == q) {
#pragma unroll
      for (int reg = 0; reg < 16; ++reg) {
        red[ch][reg * 64 + l] = acc0[reg];
        red[ch][1024 + reg * 64 + l] = acc1[reg];
      }
    }
    __syncthreads();
    if (js == 0) {
#pragma unroll
      for (int reg = 0; reg < 16; ++reg) {
        acc0[reg] += red[ch][reg * 64 + l];
        acc1[reg] += red[ch][1024 + reg * 64 + l];
      }
    }
    __syncthreads();
  }

  if (js == 0) {
#pragma unroll
    for (int reg = 0; reg < 16; ++reg) {
      const int row = (reg & 3) + 8 * (reg >> 2) + 4 * kh;
      const float rsum = (((rsl[0][row] + rsl[1][row]) + (rsl[2][row] + rsl[3][row])) +
                          ((rsl[4][row] + rsl[5][row]) + (rsl[6][row] + rsl[7][row])));
      out[(size_t)(i0 + row) * D_OUT + ch * 64 + r32] = acc0[reg] / rsum;
      out[(size_t)(i0 + row) * D_OUT + ch * 64 + 32 + r32] = acc1[reg] / rsum;
    }
  }
}

extern "C" void kernel_launch(void* const* d_in, const int* in_sizes, int n_in,
                              void* d_out, int out_size, void* d_ws, size_t ws_size,
                              hipStream_t stream) {
  const float* x     = (const float*)d_in[0];
  const int*   adj   = (const int*)d_in[1];
  const float* W     = (const float*)d_in[2];
  const float* a_src = (const float*)d_in[3];
  const float* a_dst = (const float*)d_in[4];
  float* out = (float*)d_out;

  char* ws = (char*)d_ws;
  unsigned short* xhi  = (unsigned short*)(ws);                               // 4 MB
  unsigned short* xlo  = (unsigned short*)(ws + (4 << 20));                   // 4 MB
  unsigned short* whiT = (unsigned short*)(ws + (8 << 20));                   // 64 KB
  unsigned short* wloT = (unsigned short*)(ws + (8 << 20) + (64 << 10));      // 64 KB
  unsigned short* phi  = (unsigned short*)(ws + (8 << 20) + (128 << 10));     // 2 MB
  float*          srcv = (float*)(ws + (12 << 20) + (128 << 10));             // 32 KB
  float*          dstv = (float*)(ws + (12 << 20) + (160 << 10));             // 32 KB
  unsigned long long* maskw = (unsigned long long*)(ws + (16 << 20));         // 8 MB (own region)

  // k_mask FIRST: its 256 MB stream evicts L2/L3; everything written after stays hot.
  k_mask<<<dim3(2048), dim3(256), 0, stream>>>(adj, maskw);
  k_split_x<<<dim3(1024), dim3(256), 0, stream>>>(x, xhi, xlo);
  k_split_w<<<dim3(128), dim3(256), 0, stream>>>(W, whiT, wloT);
  k_h_gemm<<<dim3(256), dim3(256), 0, stream>>>(xhi, xlo, whiT, wloT,
                                                a_src, a_dst, srcv, dstv, phi);
  k_gat<<<dim3(256), dim3(1024), 0, stream>>>(maskw, srcv, dstv, phi, out);
}

// Round 9
// 112.267 us; speedup vs baseline: 2.2546x; 1.5724x over previous
//
#include <hip/hip_runtime.h>
#include <hip/hip_bf16.h>

typedef __attribute__((ext_vector_type(8))) short bf16x8;
typedef __attribute__((ext_vector_type(4))) float f32x4;
typedef __attribute__((ext_vector_type(16))) float f32x16;

#define N_NODES 8192
#define D_IN    256
#define D_OUT   128
#define LOG2E   1.44269504088896f

__device__ __forceinline__ unsigned short bf16_rne(float f) {
  unsigned int u = __float_as_uint(f);
  u += 0x7fffu + ((u >> 16) & 1u);
  return (unsigned short)(u >> 16);
}
__device__ __forceinline__ float bf16_to_f(unsigned short s) {
  return __uint_as_float(((unsigned int)s) << 16);
}
__device__ __forceinline__ unsigned int pack_bf16x2(float lo, float hi) {
  __hip_bfloat162 b2 = __float22bfloat162_rn(make_float2(lo, hi));
  union { __hip_bfloat162 b; unsigned int u; } cv;
  cv.b = b2;
  return cv.u;
}

// ---------------- k0a: split x (fp32) -> x_hi, x_lo (bf16) ----------------
__global__ __launch_bounds__(256) void k_split_x(const float* __restrict__ x,
                                                 unsigned short* __restrict__ xhi,
                                                 unsigned short* __restrict__ xlo) {
  int idx = (blockIdx.x * 256 + threadIdx.x) * 8;
  float4 v0 = *(const float4*)(x + idx);
  float4 v1 = *(const float4*)(x + idx + 4);
  float v[8] = {v0.x, v0.y, v0.z, v0.w, v1.x, v1.y, v1.z, v1.w};
  unsigned int hw[4], lw[4];
#pragma unroll
  for (int p = 0; p < 4; ++p) {
    unsigned short h0 = bf16_rne(v[2 * p]);
    unsigned short h1 = bf16_rne(v[2 * p + 1]);
    unsigned short l0 = bf16_rne(v[2 * p] - bf16_to_f(h0));
    unsigned short l1 = bf16_rne(v[2 * p + 1] - bf16_to_f(h1));
    hw[p] = (unsigned int)h0 | ((unsigned int)h1 << 16);
    lw[p] = (unsigned int)l0 | ((unsigned int)l1 << 16);
  }
  *(uint4*)(xhi + idx) = make_uint4(hw[0], hw[1], hw[2], hw[3]);
  *(uint4*)(xlo + idx) = make_uint4(lw[0], lw[1], lw[2], lw[3]);
}

// ------------- k0b: split + transpose W -> W_hiT, W_loT [128][256] -------------
__global__ __launch_bounds__(256) void k_split_w(const float* __restrict__ W,
                                                 unsigned short* __restrict__ whiT,
                                                 unsigned short* __restrict__ wloT) {
  int c = blockIdx.x;
  int k = threadIdx.x;
  float v = W[k * D_OUT + c];
  unsigned short h = bf16_rne(v);
  unsigned short l = bf16_rne(v - bf16_to_f(h));
  whiT[c * D_IN + k] = h;
  wloT[c * D_IN + k] = l;
}

// ---- k1: h = x @ W (split-bf16 MFMA) + fused src/dst dots + B-panel pack ----
__global__ __launch_bounds__(256) void k_h_gemm(const unsigned short* __restrict__ xhi,
                                                const unsigned short* __restrict__ xlo,
                                                const unsigned short* __restrict__ whiT,
                                                const unsigned short* __restrict__ wloT,
                                                const float* __restrict__ a_src,
                                                const float* __restrict__ a_dst,
                                                float* __restrict__ srcv,
                                                float* __restrict__ dstv,
                                                unsigned short* __restrict__ phi) {
  __shared__ float h_s[32][128];
  const int t = threadIdx.x, l = t & 63, wv = t >> 6;
  const int i0 = blockIdx.x * 32;
  const int m = wv >> 1, nh = wv & 1;
  const int frow = l & 15, kq = l >> 4;
  const size_t arow = (size_t)(i0 + m * 16 + frow);
  const unsigned short* pah = xhi + arow * D_IN + kq * 8;
  const unsigned short* pal = xlo + arow * D_IN + kq * 8;
  f32x4 acc[4];
#pragma unroll
  for (int nf = 0; nf < 4; ++nf) acc[nf] = (f32x4){0.f, 0.f, 0.f, 0.f};
#pragma unroll
  for (int kk = 0; kk < 8; ++kk) {
    const int k0 = kk * 32;
    bf16x8 ah = *(const bf16x8*)(pah + k0);
    bf16x8 al = *(const bf16x8*)(pal + k0);
#pragma unroll
    for (int nf = 0; nf < 4; ++nf) {
      const int col = nh * 64 + nf * 16 + frow;
      bf16x8 bh = *(const bf16x8*)(whiT + (size_t)col * D_IN + k0 + kq * 8);
      bf16x8 bl = *(const bf16x8*)(wloT + (size_t)col * D_IN + k0 + kq * 8);
      acc[nf] = __builtin_amdgcn_mfma_f32_16x16x32_bf16(ah, bh, acc[nf], 0, 0, 0);
      acc[nf] = __builtin_amdgcn_mfma_f32_16x16x32_bf16(al, bh, acc[nf], 0, 0, 0);
      acc[nf] = __builtin_amdgcn_mfma_f32_16x16x32_bf16(ah, bl, acc[nf], 0, 0, 0);
    }
  }
#pragma unroll
  for (int nf = 0; nf < 4; ++nf)
#pragma unroll
    for (int r = 0; r < 4; ++r)
      h_s[m * 16 + kq * 4 + r][nh * 64 + nf * 16 + frow] = acc[nf][r];
  __syncthreads();

  if (t < 32) {
    float s = 0.f, d = 0.f;
#pragma unroll
    for (int c = 0; c < D_OUT; ++c) {
      float v = h_s[t][c];
      s += v * a_src[c];
      d += v * a_dst[c];
    }
    srcv[i0 + t] = s * LOG2E;
    dstv[i0 + t] = d * LOG2E;
  }

  {
    const int b = t >> 7, ct = (t >> 5) & 3, lw = t & 31;
    const size_t kg = (size_t)(i0 / 16 + b);
#pragma unroll
    for (int half = 0; half < 2; ++half) {
      const int lane = lw + 32 * half;
      unsigned int hw[4];
#pragma unroll
      for (int p = 0; p < 4; ++p) {
        float v0 = h_s[b * 16 + half * 8 + 2 * p][ct * 32 + lw];
        float v1 = h_s[b * 16 + half * 8 + 2 * p + 1][ct * 32 + lw];
        hw[p] = (unsigned int)bf16_rne(v0) | ((unsigned int)bf16_rne(v1) << 16);
      }
      const size_t off = ((kg * 4 + ct) * 64 + lane) * 8;
      *(uint4*)(phi + off) = make_uint4(hw[0], hw[1], hw[2], hw[3]);
    }
  }
}

// ---------------- k3: FUSED stream+convert+aggregate (v9) ----------------
// grid 256 (32-row tile / block), 1024 threads = 16 waves: ch = wv>>3, js = wv&7.
// Chunked pipeline over j (16 chunks x 512 j):
//   - wave wv streams rows {2wv, 2wv+1} of its block's adj slice: 16 coalesced
//     dword loads per chunk (nontemporal), ballot-packed into LDS bitmask.
//   - steady state at end of chunk c: ballot conv(c+1) (loaded a full chunk ago,
//     guaranteed landed), issue conv(c+2). MFMA iters consume mbuf[(c)&1].
//   - In-order vmcnt: B-frag waits drain behind the conv HBM queue, so the
//     kernel paces at the adj streaming roofline instead of exposed latency.
__global__ __launch_bounds__(1024) void k_gat(const int* __restrict__ adj,
                                              const float* __restrict__ srcv,
                                              const float* __restrict__ dstv,
                                              const unsigned short* __restrict__ phi,
                                              float* __restrict__ out) {
  __shared__ unsigned long long mbuf[2][8][33];  // 4.2 KB double-buffered mask chunk
  __shared__ float dstv_s[8192];                 // 32 KB
  __shared__ float red[2][2048];                 // 16 KB js-reduction buffer
  __shared__ float rsl[8][32];

  const int t = threadIdx.x, l = t & 63, wv = t >> 6;
  const int ch = wv >> 3, js = wv & 7;
  const int i0 = blockIdx.x * 32;
  const int r32 = l & 31, kh = l >> 5;

  ((float4*)dstv_s)[t] = ((const float4*)dstv)[t];
  ((float4*)dstv_s)[t + 1024] = ((const float4*)dstv)[t + 1024];
  const float s2 = srcv[i0 + r32];

  // conv: wave wv owns rows 2wv, 2wv+1; step s: row 2wv+(s>>3), word s&7, lane bit l
  const int* abase = adj + (size_t)(i0 + 2 * wv) * N_NODES + l;

  int cva[16];
  // prologue: load+ballot chunk 0, then issue chunk 1
#pragma unroll
  for (int s = 0; s < 16; ++s)
    cva[s] = __builtin_nontemporal_load(abase + (s >> 3) * N_NODES + (s & 7) * 64);
#pragma unroll
  for (int s = 0; s < 16; ++s) {
    unsigned long long b = __ballot(cva[s] > 0);
    if (l == 0) mbuf[0][s & 7][2 * wv + (s >> 3)] = b;
  }
#pragma unroll
  for (int s = 0; s < 16; ++s)
    cva[s] = __builtin_nontemporal_load(abase + (s >> 3) * N_NODES + 512 + (s & 7) * 64);

  // B panel base; strides (ushorts): chunk 65536, it 32768, ks 2048, ct 512
  const unsigned short* pb0 = phi + ((size_t)((js * 2) * 4 + ch * 2) * 64 + l) * 8;
  bf16x8 b00A = *(const bf16x8*)(pb0);
  bf16x8 b01A = *(const bf16x8*)(pb0 + 512);
  bf16x8 b10A = *(const bf16x8*)(pb0 + 2048);
  bf16x8 b11A = *(const bf16x8*)(pb0 + 2048 + 512);

  const int shl = (js & 1) * 32 + kh * 8;
  const int w0 = js >> 1;

  f32x16 acc0, acc1;
#pragma unroll
  for (int q = 0; q < 16; ++q) { acc0[q] = 0.f; acc1[q] = 0.f; }
  float rs = 0.f;

  __syncthreads();  // mbuf[0] + dstv_s ready

  for (int c = 0; c < 16; ++c) {
#pragma unroll
    for (int it = 0; it < 2; ++it) {
      // prefetch next iteration's B frags (named regs, pinned)
      int nc = c, nit = it + 1;
      if (nit == 2) { nit = 0; nc = (c < 15) ? c + 1 : 15; }
      const unsigned short* pan = pb0 + nc * 65536 + nit * 32768;
      bf16x8 b00B = *(const bf16x8*)(pan);
      bf16x8 b01B = *(const bf16x8*)(pan + 512);
      bf16x8 b10B = *(const bf16x8*)(pan + 2048);
      bf16x8 b11B = *(const bf16x8*)(pan + 2048 + 512);
      __builtin_amdgcn_sched_barrier(0);

      const unsigned long long mw = mbuf[c & 1][it * 4 + w0][r32];
      const int jl = c * 512 + it * 256 + js * 32 + kh * 8;
      const unsigned int u0 = (unsigned int)(mw >> shl) & 0xFFu;
      const unsigned int u1 = (unsigned int)(mw >> (shl + 16)) & 0xFFu;

#pragma unroll
      for (int ks = 0; ks < 2; ++ks) {
        f32x4 dva = *(const f32x4*)&dstv_s[jl + ks * 16];
        f32x4 dvb = *(const f32x4*)&dstv_s[jl + ks * 16 + 4];
        const unsigned int u = ks ? u1 : u0;
        float w[8];
#pragma unroll
        for (int e = 0; e < 4; ++e) {
          float e0 = s2 + dva[e]; e0 = fmaxf(e0, 0.2f * e0);
          float e1 = s2 + dvb[e]; e1 = fmaxf(e1, 0.2f * e1);
          w[e]     = ((u >> e) & 1u)       ? exp2f(e0) : 0.f;
          w[4 + e] = ((u >> (4 + e)) & 1u) ? exp2f(e1) : 0.f;
        }
        if (ch == 0)
          rs += ((w[0] + w[1]) + (w[2] + w[3])) + ((w[4] + w[5]) + (w[6] + w[7]));
        union { bf16x8 v; unsigned int u4[4]; } af;
#pragma unroll
        for (int p = 0; p < 4; ++p)
          af.u4[p] = pack_bf16x2(w[2 * p], w[2 * p + 1]);

        if (ks == 0) {
          acc0 = __builtin_amdgcn_mfma_f32_32x32x16_bf16(af.v, b00A, acc0, 0, 0, 0);
          acc1 = __builtin_amdgcn_mfma_f32_32x32x16_bf16(af.v, b01A, acc1, 0, 0, 0);
        } else {
          acc0 = __builtin_amdgcn_mfma_f32_32x32x16_bf16(af.v, b10A, acc0, 0, 0, 0);
          acc1 = __builtin_amdgcn_mfma_f32_32x32x16_bf16(af.v, b11A, acc1, 0, 0, 0);
        }
      }
      b00A = b00B; b01A = b01B; b10A = b10B; b11A = b11B;
    }

    // end of chunk: ballot conv(c+1) (landed; issued a full chunk ago),
    // then reissue cva for chunk c+2.
    if (c < 15) {
#pragma unroll
      for (int s = 0; s < 16; ++s) {
        unsigned long long b = __ballot(cva[s] > 0);
        if (l == 0) mbuf[(c + 1) & 1][s & 7][2 * wv + (s >> 3)] = b;
      }
      if (c < 14) {
        const int nb = (c + 2) * 512;
#pragma unroll
        for (int s = 0; s < 16; ++s)
          cva[s] = __builtin_nontemporal_load(abase + (s >> 3) * N_NODES + nb + (s & 7) * 64);
      }
    }
    __syncthreads();
  }

  // rowsum across kh halves; stash per js
  rs += __shfl_xor(rs, 32);
  if (ch == 0 && kh == 0) rsl[js][r32] = rs;

  // js-reduction of numerators: 7 serial rounds through 16 KB buffer
#pragma unroll
  for (int q = 1; q < 8; ++q) {
    if (js == q) {
#pragma unroll
      for (int reg = 0; reg < 16; ++reg) {
        red[ch][reg * 64 + l] = acc0[reg];
        red[ch][1024 + reg * 64 + l] = acc1[reg];
      }
    }
    __syncthreads();
    if (js == 0) {
#pragma unroll
      for (int reg = 0; reg < 16; ++reg) {
        acc0[reg] += red[ch][reg * 64 + l];
        acc1[reg] += red[ch][1024 + reg * 64 + l];
      }
    }
    __syncthreads();
  }

  if (js == 0) {
#pragma unroll
    for (int reg = 0; reg < 16; ++reg) {
      const int row = (reg & 3) + 8 * (reg >> 2) + 4 * kh;
      const float rsum = (((rsl[0][row] + rsl[1][row]) + (rsl[2][row] + rsl[3][row])) +
                          ((rsl[4][row] + rsl[5][row]) + (rsl[6][row] + rsl[7][row])));
      out[(size_t)(i0 + row) * D_OUT + ch * 64 + r32] = acc0[reg] / rsum;
      out[(size_t)(i0 + row) * D_OUT + ch * 64 + 32 + r32] = acc1[reg] / rsum;
    }
  }
}

extern "C" void kernel_launch(void* const* d_in, const int* in_sizes, int n_in,
                              void* d_out, int out_size, void* d_ws, size_t ws_size,
                              hipStream_t stream) {
  const float* x     = (const float*)d_in[0];
  const int*   adj   = (const int*)d_in[1];
  const float* W     = (const float*)d_in[2];
  const float* a_src = (const float*)d_in[3];
  const float* a_dst = (const float*)d_in[4];
  float* out = (float*)d_out;

  char* ws = (char*)d_ws;
  unsigned short* xhi  = (unsigned short*)(ws);                               // 4 MB
  unsigned short* xlo  = (unsigned short*)(ws + (4 << 20));                   // 4 MB
  unsigned short* whiT = (unsigned short*)(ws + (8 << 20));                   // 64 KB
  unsigned short* wloT = (unsigned short*)(ws + (8 << 20) + (64 << 10));      // 64 KB
  unsigned short* phi  = (unsigned short*)(ws + (8 << 20) + (128 << 10));     // 2 MB
  float*          srcv = (float*)(ws + (12 << 20) + (128 << 10));             // 32 KB
  float*          dstv = (float*)(ws + (12 << 20) + (160 << 10));             // 32 KB

  k_split_x<<<dim3(1024), dim3(256), 0, stream>>>(x, xhi, xlo);
  k_split_w<<<dim3(128), dim3(256), 0, stream>>>(W, whiT, wloT);
  k_h_gemm<<<dim3(256), dim3(256), 0, stream>>>(xhi, xlo, whiT, wloT,
                                                a_src, a_dst, srcv, dstv, phi);
  k_gat<<<dim3(256), dim3(1024), 0, stream>>>(adj, srcv, dstv, phi, out);
}